// Round 7
// baseline (2217.058 us; speedup 1.0000x reference)
//
#include <hip/hip_runtime.h>
#include <math.h>

// Problem constants
#define NG   512      // graphs
#define NPG  128      // nodes/graph
#define NN   65536    // nodes
#define DD   512      // feature dim
#define KK   1024     // codebook
#define HH   128      // hidden
#define TT   10       // classes

#define RES_TAU 1.0f  // rescue margin threshold (approx d2 error bound ~0.03; 30x safety)
#define RES_CAP 65536

typedef __attribute__((ext_vector_type(8))) short short8;
typedef __attribute__((ext_vector_type(4))) float float4v;
// ext-vector types for __builtin_nontemporal_* (HIP_vector_type classes are rejected)
typedef __attribute__((ext_vector_type(4))) float        f32x4;
typedef __attribute__((ext_vector_type(4))) unsigned int u32x4;
typedef __attribute__((ext_vector_type(4))) unsigned short u16x4;

// Output layout (element offsets, fp32)
static const long OFF_CPRE = 0;                       // [512,10]
static const long OFF_KPRE = 5120;                    // [512,10]
static const long OFF_YPRE = 10240;                   // [512,10]
static const long OFF_AORI = 15360;                   // [512,128,128]
static const long OFF_AREC = OFF_AORI + 8388608L;     // [512,128,128]
static const long OFF_Z    = OFF_AREC + 8388608L;     // [65536,512]
static const long OFF_X    = OFF_Z + 33554432L;       // [65536,512]
static const long OFF_CD   = OFF_X + 33554432L;       // [1024,1024]
static const long OFF_CM   = OFF_CD + 1048576L;       // [1024,1024]
static const long OFF_PC   = OFF_CM + 1048576L;       // [512,512]
static const long OFF_PX   = OFF_PC + 262144L;        // [512,512]

__device__ __forceinline__ float sigm_fast(float v) { return 1.0f / (1.0f + __expf(-v)); }
__device__ __forceinline__ float sigm_acc (float v) { return 1.0f / (1.0f + expf(-v)); }

// ---- diag/off-diag masks + diag vector --------------------------------------
__global__ void k_diagmask(const float* __restrict__ causal,
                           float* __restrict__ cd, float* __restrict__ cm,
                           float* __restrict__ dv) {
  int i = blockIdx.x * 256 + threadIdx.x;      // over K*K
  int r = i >> 10, c = i & 1023;
  float v = causal[i];
  bool diag = (r == c);
  cd[i] = diag ? v : 0.0f;
  cm[i] = diag ? 0.0f : v;
  if (diag) dv[r] = v;
}

// ---- fc1: h = sigmoid(cbi @ fc1_w^T + b)  [1024,128] ------------------------
__global__ void k_fc1(const float* __restrict__ cbi, const float* __restrict__ w,
                      const float* __restrict__ b, float* __restrict__ h) {
  int i = blockIdx.x * 256 + threadIdx.x;      // 131072
  int k = i >> 7, j = i & 127;
  const float4* xr = (const float4*)(cbi + (long)k * DD);
  const float4* wr = (const float4*)(w + (long)j * DD);
  float s = b[j];
  for (int d = 0; d < DD / 4; d++) {
    float4 a = xr[d], bb = wr[d];
    s += a.x * bb.x + a.y * bb.y + a.z * bb.z + a.w * bb.w;
  }
  h[i] = sigm_acc(s);
}

// ---- fc2: ct = h @ fc2_w^T + b ; cs = sigmoid(ct)  [1024,512] ---------------
__global__ void k_fc2(const float* __restrict__ h, const float* __restrict__ w,
                      const float* __restrict__ b, float* __restrict__ ct,
                      float* __restrict__ cs) {
  int i = blockIdx.x * 256 + threadIdx.x;      // 524288
  int k = i >> 9, d = i & 511;
  const float4* hr = (const float4*)(h + (long)k * HH);
  const float4* wr = (const float4*)(w + (long)d * HH);
  float s = b[d];
  for (int j = 0; j < HH / 4; j++) {
    float4 a = hr[j], bb = wr[j];
    s += a.x * bb.x + a.y * bb.y + a.z * bb.z + a.w * bb.w;
  }
  ct[i] = s;
  cs[i] = sigm_acc(s);
}

// ---- generic tiled SGEMM: C[M,Nc] = Af(A) @ Bf(B) ---------------------------
template <int AM, int BM>
__launch_bounds__(256)
__global__ void gemm64(const float* __restrict__ A, const float* __restrict__ B,
                       const float* __restrict__ dscale, float* __restrict__ C,
                       int M, int Nc, int Kr) {
  __shared__ __align__(16) float as[32][68];   // [kr][m]
  __shared__ __align__(16) float bs[32][68];   // [kr][n]
  int tid = threadIdx.x;
  int tx = tid & 15, ty = tid >> 4;
  int m0 = blockIdx.y * 64, n0 = blockIdx.x * 64;
  float acc[4][4] = {};
  for (int kt = 0; kt < Kr; kt += 32) {
    for (int s = tid; s < 512; s += 256) {
      int m = s >> 3, c4 = (s & 7) << 2;
      int gr = m0 + m, gc = kt + c4;
      float4 v = *(const float4*)&A[(long)gr * Kr + gc];
      float vv[4] = {v.x, v.y, v.z, v.w};
      if (AM == 1) {
#pragma unroll
        for (int q = 0; q < 4; q++) if (gc + q == gr) vv[q] = 1.0f;
      } else if (AM == 2) {
#pragma unroll
        for (int q = 0; q < 4; q++) if (gc + q == gr) vv[q] = 0.0f;
      }
      as[c4 + 0][m] = vv[0]; as[c4 + 1][m] = vv[1];
      as[c4 + 2][m] = vv[2]; as[c4 + 3][m] = vv[3];
    }
    for (int s = tid; s < 512; s += 256) {
      int r = s >> 4, c4 = (s & 15) << 2;
      float4 v = *(const float4*)&B[(long)(kt + r) * Nc + n0 + c4];
      if (BM == 1) {
        float sc = dscale[kt + r];
        v.x *= sc; v.y *= sc; v.z *= sc; v.w *= sc;
      }
      *(float4*)&bs[r][c4] = v;
    }
    __syncthreads();
#pragma unroll
    for (int r = 0; r < 32; r++) {
      float4 a4 = *(const float4*)&as[r][ty * 4];
      float4 b4 = *(const float4*)&bs[r][tx * 4];
      float av[4] = {a4.x, a4.y, a4.z, a4.w};
      float bv[4] = {b4.x, b4.y, b4.z, b4.w};
#pragma unroll
      for (int i = 0; i < 4; i++)
#pragma unroll
        for (int j = 0; j < 4; j++) acc[i][j] += av[i] * bv[j];
    }
    __syncthreads();
  }
#pragma unroll
  for (int i = 0; i < 4; i++) {
    float4 v = make_float4(acc[i][0], acc[i][1], acc[i][2], acc[i][3]);
    *(float4*)&C[(long)(m0 + ty * 4 + i) * Nc + n0 + tx * 4] = v;
  }
}

// ---- fused dual SGEMM: Cz = zerodiag(A) @ B ; Ci = identdiag(A) @ (dscale⊙B)
__launch_bounds__(256)
__global__ void gemm64_dual(const float* __restrict__ A, const float* __restrict__ B,
                            const float* __restrict__ dscale,
                            float* __restrict__ Cz, float* __restrict__ Ci,
                            int M, int Nc, int Kr) {
  __shared__ __align__(16) float asZ[32][68];  // zero-diag A   [kr][m]
  __shared__ __align__(16) float asI[32][68];  // ident-diag A  [kr][m]
  __shared__ __align__(16) float bs[32][68];   // raw B         [kr][n]
  __shared__ float dsc[32];
  int tid = threadIdx.x;
  int tx = tid & 15, ty = tid >> 4;
  int m0 = blockIdx.y * 64, n0 = blockIdx.x * 64;
  float accZ[4][4] = {};
  float accI[4][4] = {};
  for (int kt = 0; kt < Kr; kt += 32) {
    for (int s = tid; s < 512; s += 256) {
      int m = s >> 3, c4 = (s & 7) << 2;
      int gr = m0 + m, gc = kt + c4;
      float4 v = *(const float4*)&A[(long)gr * Kr + gc];
      float vz[4] = {v.x, v.y, v.z, v.w};
      float vi[4] = {v.x, v.y, v.z, v.w};
#pragma unroll
      for (int q = 0; q < 4; q++) if (gc + q == gr) { vz[q] = 0.0f; vi[q] = 1.0f; }
      asZ[c4 + 0][m] = vz[0]; asZ[c4 + 1][m] = vz[1];
      asZ[c4 + 2][m] = vz[2]; asZ[c4 + 3][m] = vz[3];
      asI[c4 + 0][m] = vi[0]; asI[c4 + 1][m] = vi[1];
      asI[c4 + 2][m] = vi[2]; asI[c4 + 3][m] = vi[3];
    }
    for (int s = tid; s < 512; s += 256) {
      int r = s >> 4, c4 = (s & 15) << 2;
      float4 v = *(const float4*)&B[(long)(kt + r) * Nc + n0 + c4];
      *(float4*)&bs[r][c4] = v;
    }
    if (tid < 32) dsc[tid] = dscale[kt + tid];
    __syncthreads();
#pragma unroll
    for (int r = 0; r < 32; r++) {
      float4 aZ = *(const float4*)&asZ[r][ty * 4];
      float4 aI = *(const float4*)&asI[r][ty * 4];
      float4 b4 = *(const float4*)&bs[r][tx * 4];
      float sc = dsc[r];
      float az[4] = {aZ.x, aZ.y, aZ.z, aZ.w};
      float ai[4] = {aI.x, aI.y, aI.z, aI.w};
      float bz[4] = {b4.x, b4.y, b4.z, b4.w};
      float bi[4] = {b4.x * sc, b4.y * sc, b4.z * sc, b4.w * sc};
#pragma unroll
      for (int i = 0; i < 4; i++)
#pragma unroll
        for (int j = 0; j < 4; j++) {
          accZ[i][j] += az[i] * bz[j];
          accI[i][j] += ai[i] * bi[j];
        }
    }
    __syncthreads();
  }
#pragma unroll
  for (int i = 0; i < 4; i++) {
    float4 vz = make_float4(accZ[i][0], accZ[i][1], accZ[i][2], accZ[i][3]);
    float4 vi = make_float4(accI[i][0], accI[i][1], accI[i][2], accI[i][3]);
    *(float4*)&Cz[(long)(m0 + ty * 4 + i) * Nc + n0 + tx * 4] = vz;
    *(float4*)&Ci[(long)(m0 + ty * 4 + i) * Nc + n0 + tx * 4] = vi;
  }
}

// ---- row sum-of-squares of ccb -> cn2[1024]; also zero rescue counter -------
__global__ void k_cnorm(const float* __restrict__ ccb, float* __restrict__ cn2,
                        int* __restrict__ rc) {
  if (blockIdx.x == 0 && threadIdx.x == 0) *rc = 0;
  int row = blockIdx.x * 4 + (threadIdx.x >> 6);
  int lane = threadIdx.x & 63;
  const float* r = ccb + (long)row * DD;
  float s = 0.0f;
  for (int q = 0; q < DD; q += 64) { float v = r[lane + q]; s += v * v; }
  for (int off = 32; off > 0; off >>= 1) s += __shfl_down(s, off);
  if (lane == 0) cn2[row] = s;
}

// ---- split fp32 -> bf16 hi + bf16 lo (RNE, manual bit twiddling) ------------
__device__ __forceinline__ ushort bf16_rne(float f, float* back) {
  unsigned int b = __float_as_uint(f);
  unsigned int r = b + 0x7fffu + ((b >> 16) & 1u);
  ushort h = (ushort)(r >> 16);
  *back = __uint_as_float(((unsigned int)h) << 16);
  return h;
}

// codes split: cached normally (codes must stay L2-resident for argmin)
__global__ void k_split(const float4* __restrict__ src, ushort* __restrict__ hi,
                        ushort* __restrict__ lo, long n4) {
  long i = (long)blockIdx.x * 256 + threadIdx.x;
  if (i >= n4) return;
  float4 v = src[i];
  float vv[4] = {v.x, v.y, v.z, v.w};
  ushort h[4], l[4];
#pragma unroll
  for (int q = 0; q < 4; q++) {
    float back;
    h[q] = bf16_rne(vv[q], &back);
    float rem = vv[q] - back;
    float dummy;
    l[q] = bf16_rne(rem, &dummy);
  }
  ((ushort4*)hi)[i] = make_ushort4(h[0], h[1], h[2], h[3]);
  ((ushort4*)lo)[i] = make_ushort4(l[0], l[1], l[2], l[3]);
}

// x split: pure stream, no reuse -> non-temporal both sides (keep L2 for codes)
__global__ void k_split_nt(const float* __restrict__ src, ushort* __restrict__ hi,
                           ushort* __restrict__ lo, long n4) {
  long i = (long)blockIdx.x * 256 + threadIdx.x;
  if (i >= n4) return;
  f32x4 v = __builtin_nontemporal_load((const f32x4*)src + i);
  ushort h[4], l[4];
#pragma unroll
  for (int q = 0; q < 4; q++) {
    float back;
    h[q] = bf16_rne(v[q], &back);
    float rem = v[q] - back;
    float dummy;
    l[q] = bf16_rne(rem, &dummy);
  }
  u16x4 hv = {h[0], h[1], h[2], h[3]};
  u16x4 lv = {l[0], l[1], l[2], l[3]};
  __builtin_nontemporal_store(hv, (u16x4*)hi + i);
  __builtin_nontemporal_store(lv, (u16x4*)lo + i);
}

// ---- MFMA split-bf16 argmin: d2[n,k] = cn2[k] - 2 * x_n . ccb_k -------------
// High-occupancy streaming design: 4096 blocks x 256 thr (4 waves), 16-node
// x tiles in LDS (33 KB) -> 4 blocks/CU = 16 waves/CU = 4 waves/SIMD (2x the
// previous TLP; latency hiding now comes from wave interleave, not pinned
// scheduling). Each wave: i=1 (16 nodes) x j=4 (64-code strip), 4 chunks
// covering all 1024 codes. B streamed from the L2-resident code table with
// compile-time k offsets (fully unrolled k loop). Numerics bit-identical:
// same k order, same hh/hl/lh MFMA chain, same comparators.
__launch_bounds__(256, 4)
__global__ void k_argmin_mfma(const ushort* __restrict__ xh, const ushort* __restrict__ xl,
                              const ushort* __restrict__ ch, const ushort* __restrict__ cl,
                              const float* __restrict__ cn2, int* __restrict__ idxg,
                              int* __restrict__ rc, int* __restrict__ rlist) {
  __shared__ __align__(16) ushort xsh[16 * 512];   // 16 KB, row = 1KB
  __shared__ __align__(16) ushort xsl[16 * 512];   // 16 KB
  __shared__ float mm1[4][16], mm2[4][16];         // 512 B
  __shared__ int   mid[4][16];                     // 256 B

  int tid = threadIdx.x;
  long n0 = (long)blockIdx.x * 16;

  // ---- prologue: stage x tile (hi+lo) into LDS, swizzled, non-temporal ----
  // 32 rows (16 hi + 16 lo) x 64 granules(16B) = 2048; 8 per thread.
  u32x4 tmp[8];
#pragma unroll
  for (int r = 0; r < 8; r++) {
    int g = tid + r * 256;                  // 0..2047
    int rid = g >> 6;                       // 0..31
    int node = rid & 15;
    int gb = (g & 63) << 4;                 // byte within row
    const ushort* src = ((rid < 16) ? xh : xl) + (n0 + node) * (long)DD;
    tmp[r] = __builtin_nontemporal_load((const u32x4*)((const char*)src + gb));
  }
#pragma unroll
  for (int r = 0; r < 8; r++) {
    int g = tid + r * 256;
    int rid = g >> 6;
    int node = rid & 15;
    int gb = (g & 63) << 4;
    int db = gb ^ ((node & 7) << 4);        // XOR swizzle (write side)
    ushort* dst = (rid < 16) ? xsh : xsl;
    *(u32x4*)((char*)dst + node * 1024 + db) = tmp[r];
  }
  __syncthreads();

  int lane = tid & 63, wave = tid >> 6;     // 4 waves
  int col = lane & 15, quad = lane >> 4;

  // per-lane LDS byte base for A fragment (node = col): addr(k) = abase ^ (k<<6)
  int abase = col * 1024 + ((quad ^ (col & 3)) << 4) + (((col >> 2) & 1) << 6);

  // per-lane B pointers, j-indexed (compile-time idx only): row = cb0 + j*16 + col
  const ushort* pBh[4];
  const ushort* pBl[4];
#pragma unroll
  for (int j = 0; j < 4; j++) {
    long row = (long)(wave * 64 + j * 16 + col);
    pBh[j] = ch + row * DD + quad * 8;
    pBl[j] = cl + row * DD + quad * 8;
  }

  float m1[4], m2[4]; int id1[4];
#pragma unroll
  for (int s = 0; s < 4; s++) { m1[s] = 3.4e38f; m2[s] = 3.4e38f; id1[s] = 0; }

  const float4v vzero = {0.0f, 0.0f, 0.0f, 0.0f};
  float4v acc[4];

#pragma unroll 1
  for (int cc = 0; cc < 4; cc++) {
#pragma unroll
    for (int j = 0; j < 4; j++) acc[j] = vzero;

#pragma unroll
    for (int k = 0; k < 16; k++) {
      // A fragment from swizzled LDS (conflict-free b128)
      int ao = abase ^ (k << 6);
      short8 aH = *(const short8*)((const char*)xsh + ao);
      short8 aL = *(const short8*)((const char*)xsl + ao);
      // B fragments straight from global (codes are L2-resident); k*32
      // element offset folds into the load's immediate offset field.
      short8 bh[4], bl[4];
#pragma unroll
      for (int j = 0; j < 4; j++) {
        bh[j] = *(const short8*)(pBh[j] + k * 32);
        bl[j] = *(const short8*)(pBl[j] + k * 32);
      }
      __builtin_amdgcn_s_setprio(1);
#pragma unroll
      for (int j = 0; j < 4; j++) {
        acc[j] = __builtin_amdgcn_mfma_f32_16x16x32_bf16(aH, bh[j], acc[j], 0, 0, 0);
        acc[j] = __builtin_amdgcn_mfma_f32_16x16x32_bf16(aH, bl[j], acc[j], 0, 0, 0);
        acc[j] = __builtin_amdgcn_mfma_f32_16x16x32_bf16(aL, bh[j], acc[j], 0, 0, 0);
      }
      __builtin_amdgcn_s_setprio(0);
    }

    // epilogue: fold this chunk into per-slot top-2
    int cb0 = cc * 256 + wave * 64;
#pragma unroll
    for (int j = 0; j < 4; j++) {
      int code = cb0 + j * 16 + col;
      float c2 = cn2[code];
#pragma unroll
      for (int r = 0; r < 4; r++) {
        float v = fmaf(-2.0f, acc[j][r], c2);
        if (v < m1[r] || (v == m1[r] && code < id1[r])) {
          m2[r] = m1[r]; m1[r] = v; id1[r] = code;
        } else if (v < m2[r]) {
          m2[r] = v;
        }
      }
    }
    // advance B pointers to next 256-code chunk
#pragma unroll
    for (int j = 0; j < 4; j++) { pBh[j] += 256 * DD; pBl[j] += 256 * DD; }
  }

  // cross-lane top-2 merge over the 16 lanes of each quad-group
#pragma unroll
  for (int s = 0; s < 4; s++) {
#pragma unroll
    for (int mask = 1; mask <= 8; mask <<= 1) {
      float om1 = __shfl_xor(m1[s], mask);
      float om2 = __shfl_xor(m2[s], mask);
      int   oid = __shfl_xor(id1[s], mask);
      if (om1 < m1[s] || (om1 == m1[s] && oid < id1[s])) {
        m2[s] = fminf(m1[s], om2); m1[s] = om1; id1[s] = oid;
      } else {
        m2[s] = fminf(m2[s], om1);
      }
    }
  }
  if (col == 0) {   // lanes 0,16,32,48: one writer per quad
#pragma unroll
    for (int s = 0; s < 4; s++) {
      int nl = quad * 4 + s;                // node within tile (0..15)
      mm1[wave][nl] = m1[s]; mm2[wave][nl] = m2[s]; mid[wave][nl] = id1[s];
    }
  }
  __syncthreads();
  if (tid < 16) {
    float f1 = mm1[0][tid], f2 = mm2[0][tid]; int fi = mid[0][tid];
#pragma unroll
    for (int w = 1; w < 4; w++) {
      float b1 = mm1[w][tid], b2 = mm2[w][tid]; int bi = mid[w][tid];
      if (b1 < f1 || (b1 == f1 && bi < fi)) {
        f2 = fminf(f1, b2); f1 = b1; fi = bi;
      } else {
        f2 = fminf(f2, b1);
      }
    }
    idxg[n0 + tid] = fi;
    if (f2 - f1 < RES_TAU) {
      int p = atomicAdd(rc, 1);
      if (p < RES_CAP) rlist[p] = (int)(n0 + tid);
    }
  }
}

// ---- exact fp32 rescue for near-tie nodes -----------------------------------
__global__ void k_rescue(const float* __restrict__ x, const float* __restrict__ ccb,
                         const float* __restrict__ cn2, const int* __restrict__ rc,
                         const int* __restrict__ rlist, int* __restrict__ idxg) {
  __shared__ float xs[DD];
  __shared__ float bv[256]; __shared__ int bi[256];
  int count = *rc; if (count > RES_CAP) count = RES_CAP;
  int tid = threadIdx.x;
  for (int f = blockIdx.x; f < count; f += gridDim.x) {
    int n = rlist[f];
    for (int s = tid; s < DD; s += 256) xs[s] = x[(long)n * DD + s];
    __syncthreads();
    float best = 3.4e38f; int besti = 0;
    for (int c = tid; c < KK; c += 256) {
      const float4* cr = (const float4*)(ccb + (long)c * DD);
      const float4* xr = (const float4*)xs;
      float dot = 0.0f;
      for (int d = 0; d < DD / 4; d++) {
        float4 a = xr[d], b = cr[d];
        dot += a.x * b.x + a.y * b.y + a.z * b.z + a.w * b.w;
      }
      float v = cn2[c] - 2.0f * dot;
      if (v < best || (v == best && c < besti)) { best = v; besti = c; }
    }
    bv[tid] = best; bi[tid] = besti;
    __syncthreads();
    for (int off = 128; off > 0; off >>= 1) {
      if (tid < off) {
        float ov = bv[tid + off]; int oi = bi[tid + off];
        if (ov < bv[tid] || (ov == bv[tid] && oi < bi[tid])) { bv[tid] = ov; bi[tid] = oi; }
      }
      __syncthreads();
    }
    if (tid == 0) idxg[n] = bi[0];
    __syncthreads();
  }
}

// ---- z gather: z[n,:] = ct[idx[n],:] ----------------------------------------
__global__ void k_gather(const float4* __restrict__ ct4, const int* __restrict__ idxg,
                         float4* __restrict__ z4) {
  long i = (long)blockIdx.x * 256 + threadIdx.x;  // over NN*128 float4
  int n = (int)(i >> 7), c = (int)(i & 127);
  z4[i] = ct4[(long)idxg[n] * 128 + c];
}

// ---- pooled means -----------------------------------------------------------
__global__ void k_pool(const float* __restrict__ x, const float* __restrict__ ccb,
                       const float* __restrict__ kcb, const int* __restrict__ idxg,
                       float* __restrict__ px, float* __restrict__ pc,
                       float* __restrict__ pk) {
  __shared__ int sidx[NPG];
  int g = blockIdx.x, tid = threadIdx.x;   // 512 threads
  if (tid < NPG) sidx[tid] = idxg[g * NPG + tid];
  __syncthreads();
  int d = tid;
  float sx = 0.0f, sc = 0.0f, sk = 0.0f;
  for (int n = 0; n < NPG; n++) {
    sx += x[((long)g * NPG + n) * DD + d];
    long r = (long)sidx[n] * DD + d;
    sc += ccb[r]; sk += kcb[r];
  }
  px[(long)g * DD + d] = sx / 128.0f;
  pc[(long)g * DD + d] = (sx + sc) / 128.0f;
  pk[(long)g * DD + d] = sk / 128.0f;
}

// ---- classifier heads -------------------------------------------------------
__global__ void k_heads(const float* __restrict__ pc, const float* __restrict__ pk,
                        const float* __restrict__ px, const float* __restrict__ w,
                        const float* __restrict__ b, float* __restrict__ cpre,
                        float* __restrict__ kpre, float* __restrict__ ypre) {
  int g = blockIdx.x, t = threadIdx.x;   // 64 threads, 30 active
  if (t >= 30) return;
  int which = t / 10, tt = t % 10;
  const float* src = (which == 0) ? pc : ((which == 1) ? pk : px);
  const float* sr = src + (long)g * DD;
  const float* wr = w + (long)tt * DD;
  float s = 0.0f;
  for (int d = 0; d < DD; d++) s += sr[d] * wr[d];
  s += b[tt];
  float* dst = (which == 0) ? cpre : ((which == 1) ? kpre : ypre);
  dst[g * TT + tt] = s;
}

// ---- x passthrough (pure stream -> non-temporal) ----------------------------
__global__ void k_copy(const float* __restrict__ src, float* __restrict__ dst) {
  long i = (long)blockIdx.x * 256 + threadIdx.x;
  f32x4 v = __builtin_nontemporal_load((const f32x4*)src + i);
  __builtin_nontemporal_store(v, (f32x4*)dst + i);
}

// ---- per-graph adjacency: sigmoid(norm(Z) @ norm(Z)^T / 0.1) ----------------
__launch_bounds__(256)
__global__ void k_adj(const float* __restrict__ Z, float* __restrict__ Aout) {
  __shared__ float nrm[NPG];
  __shared__ float inv[NPG];
  __shared__ __align__(16) float zs[32][132];  // [d][node]
  int tid = threadIdx.x;
  int g = blockIdx.x;
  const float* base = Z + (long)g * NPG * DD;
  if (tid < NPG) nrm[tid] = 0.0f;
  __syncthreads();
  for (int k = 0; k < 64; k++) {
    long i = (long)k * 256 + tid;                 // float4 index, 16384 total
    int n = (int)(i >> 7);
    float4 v = ((const float4*)base)[i];
    float s = v.x * v.x + v.y * v.y + v.z * v.z + v.w * v.w;
    for (int off = 32; off > 0; off >>= 1) s += __shfl_down(s, off);
    if ((tid & 63) == 0) atomicAdd(&nrm[n], s);
  }
  __syncthreads();
  if (tid < NPG) inv[tid] = 1.0f / fmaxf(sqrtf(nrm[tid]), 1e-12f);
  __syncthreads();
  float acc[8][8] = {};
  int tx = tid & 15, ty = tid >> 4;
  for (int dt = 0; dt < DD; dt += 32) {
    for (int s = tid; s < 1024; s += 256) {
      int n = s >> 3, c4 = (s & 7) << 2;
      float4 v = *(const float4*)&base[(long)n * DD + dt + c4];
      float iv = inv[n];
      zs[c4 + 0][n] = v.x * iv; zs[c4 + 1][n] = v.y * iv;
      zs[c4 + 2][n] = v.z * iv; zs[c4 + 3][n] = v.w * iv;
    }
    __syncthreads();
#pragma unroll 8
    for (int r = 0; r < 32; r++) {
      float rv[8], cv[8];
      *(float4*)&rv[0] = *(const float4*)&zs[r][ty * 8];
      *(float4*)&rv[4] = *(const float4*)&zs[r][ty * 8 + 4];
      *(float4*)&cv[0] = *(const float4*)&zs[r][tx * 8];
      *(float4*)&cv[4] = *(const float4*)&zs[r][tx * 8 + 4];
#pragma unroll
      for (int i = 0; i < 8; i++)
#pragma unroll
        for (int j = 0; j < 8; j++) acc[i][j] += rv[i] * cv[j];
    }
    __syncthreads();
  }
  float* aout = Aout + (long)g * NPG * NPG;
#pragma unroll
  for (int i = 0; i < 8; i++) {
    int rr = ty * 8 + i;
    float o[8];
#pragma unroll
    for (int j = 0; j < 8; j++) o[j] = sigm_fast(acc[i][j] * 10.0f);
    *(float4*)&aout[(long)rr * NPG + tx * 8]     = make_float4(o[0], o[1], o[2], o[3]);
    *(float4*)&aout[(long)rr * NPG + tx * 8 + 4] = make_float4(o[4], o[5], o[6], o[7]);
  }
}

extern "C" void kernel_launch(void* const* d_in, const int* in_sizes, int n_in,
                              void* d_out, int out_size, void* d_ws, size_t ws_size,
                              hipStream_t stream) {
  const float* x      = (const float*)d_in[0];
  const float* cbi    = (const float*)d_in[2];
  const float* fc1w   = (const float*)d_in[3];
  const float* fc1b   = (const float*)d_in[4];
  const float* fc2w   = (const float*)d_in[5];
  const float* fc2b   = (const float*)d_in[6];
  const float* causal = (const float*)d_in[7];
  const float* clsw   = (const float*)d_in[8];
  const float* clsb   = (const float*)d_in[9];
  float* out = (float*)d_out;

  float* cpre = out + OFF_CPRE;
  float* kpre = out + OFF_KPRE;
  float* ypre = out + OFF_YPRE;

  // scratch carved out of the A_ori region (overwritten by final k_adj)
  float* scr  = out + OFF_AORI;
  float* h    = scr;
  float* cs   = scr + 131072L;
  float* tmp2 = scr + 655360L;
  float* ccb  = scr + 1179648L;
  float* kcb  = scr + 1703936L;
  float* cn2  = scr + 2228224L;
  int*   idxg = (int*)(scr + 2229248L);
  float* pk   = scr + 2294784L;
  float* dv   = scr + 2556928L;
  ushort* ch  = (ushort*)(scr + 2557952L);  // 1024x512 bf16 hi (262144 floats)
  ushort* cl  = (ushort*)(scr + 2820096L);  // 1024x512 bf16 lo
  int*   rc   = (int*)(scr + 3082240L);     // rescue counter
  int*   rlist= (int*)(scr + 3082496L);     // rescue list (65536 ints)
  float* ct   = out + OFF_AREC;             // lives in A_rec region until gather done
  // x hi/lo split lives in the X output region until k_copy (runs after argmin+rescue)
  ushort* xh  = (ushort*)(out + OFF_X);                 // 65536x512 bf16 hi
  ushort* xl  = (ushort*)(out + OFF_X + 16777216L);     // 65536x512 bf16 lo

  k_diagmask<<<4096, 256, 0, stream>>>(causal, out + OFF_CD, out + OFF_CM, dv);
  k_fc1<<<512, 256, 0, stream>>>(cbi, fc1w, fc1b, h);
  k_fc2<<<2048, 256, 0, stream>>>(h, fc2w, fc2b, ct, cs);
  gemm64_dual<<<dim3(8, 16), 256, 0, stream>>>(causal, cs, dv, tmp2, ccb, KK, DD, KK);
  gemm64<1, 0><<<dim3(8, 16), 256, 0, stream>>>(causal, tmp2, nullptr, kcb, KK, DD, KK);
  k_cnorm<<<256, 256, 0, stream>>>(ccb, cn2, rc);
  k_split_nt<<<32768, 256, 0, stream>>>(x, xh, xl, 8388608L);
  k_split<<<512, 256, 0, stream>>>((const float4*)ccb, ch, cl, 131072L);
  k_argmin_mfma<<<4096, 256, 0, stream>>>(xh, xl, ch, cl, cn2, idxg, rc, rlist);
  k_rescue<<<128, 256, 0, stream>>>(x, ccb, cn2, rc, rlist, idxg);
  k_gather<<<32768, 256, 0, stream>>>((const float4*)ct, idxg, (float4*)(out + OFF_Z));
  k_pool<<<512, 512, 0, stream>>>(x, ccb, kcb, idxg, out + OFF_PX, out + OFF_PC, pk);
  k_heads<<<512, 64, 0, stream>>>(out + OFF_PC, pk, out + OFF_PX, clsw, clsb, cpre, kpre, ypre);
  k_copy<<<32768, 256, 0, stream>>>(x, out + OFF_X);
  k_adj<<<512, 256, 0, stream>>>(out + OFF_Z, out + OFF_AREC);  // overwrites ct (done)
  k_adj<<<512, 256, 0, stream>>>(x, out + OFF_AORI);            // overwrites scratch (done)
}

// Round 8
// 1530.846 us; speedup vs baseline: 1.4483x; 1.4483x over previous
//
#include <hip/hip_runtime.h>
#include <math.h>

// Problem constants
#define NG   512      // graphs
#define NPG  128      // nodes/graph
#define NN   65536    // nodes
#define DD   512      // feature dim
#define KK   1024     // codebook
#define HH   128      // hidden
#define TT   10       // classes

#define RES_TAU 1.0f  // rescue margin threshold (approx d2 error bound ~0.03; 30x safety)
#define RES_CAP 65536

typedef __attribute__((ext_vector_type(8))) short short8;
typedef __attribute__((ext_vector_type(4))) float float4v;
// ext-vector types for __builtin_nontemporal_* (HIP_vector_type classes are rejected)
typedef __attribute__((ext_vector_type(4))) float        f32x4;
typedef __attribute__((ext_vector_type(4))) unsigned int u32x4;
typedef __attribute__((ext_vector_type(4))) unsigned short u16x4;

// Output layout (element offsets, fp32)
static const long OFF_CPRE = 0;                       // [512,10]
static const long OFF_KPRE = 5120;                    // [512,10]
static const long OFF_YPRE = 10240;                   // [512,10]
static const long OFF_AORI = 15360;                   // [512,128,128]
static const long OFF_AREC = OFF_AORI + 8388608L;     // [512,128,128]
static const long OFF_Z    = OFF_AREC + 8388608L;     // [65536,512]
static const long OFF_X    = OFF_Z + 33554432L;       // [65536,512]
static const long OFF_CD   = OFF_X + 33554432L;       // [1024,1024]
static const long OFF_CM   = OFF_CD + 1048576L;       // [1024,1024]
static const long OFF_PC   = OFF_CM + 1048576L;       // [512,512]
static const long OFF_PX   = OFF_PC + 262144L;        // [512,512]

__device__ __forceinline__ float sigm_fast(float v) { return 1.0f / (1.0f + __expf(-v)); }
__device__ __forceinline__ float sigm_acc (float v) { return 1.0f / (1.0f + expf(-v)); }

// ---- diag/off-diag masks + diag vector --------------------------------------
__global__ void k_diagmask(const float* __restrict__ causal,
                           float* __restrict__ cd, float* __restrict__ cm,
                           float* __restrict__ dv) {
  int i = blockIdx.x * 256 + threadIdx.x;      // over K*K
  int r = i >> 10, c = i & 1023;
  float v = causal[i];
  bool diag = (r == c);
  cd[i] = diag ? v : 0.0f;
  cm[i] = diag ? 0.0f : v;
  if (diag) dv[r] = v;
}

// ---- fc1: h = sigmoid(cbi @ fc1_w^T + b)  [1024,128] ------------------------
__global__ void k_fc1(const float* __restrict__ cbi, const float* __restrict__ w,
                      const float* __restrict__ b, float* __restrict__ h) {
  int i = blockIdx.x * 256 + threadIdx.x;      // 131072
  int k = i >> 7, j = i & 127;
  const float4* xr = (const float4*)(cbi + (long)k * DD);
  const float4* wr = (const float4*)(w + (long)j * DD);
  float s = b[j];
  for (int d = 0; d < DD / 4; d++) {
    float4 a = xr[d], bb = wr[d];
    s += a.x * bb.x + a.y * bb.y + a.z * bb.z + a.w * bb.w;
  }
  h[i] = sigm_acc(s);
}

// ---- fc2: ct = h @ fc2_w^T + b ; cs = sigmoid(ct)  [1024,512] ---------------
__global__ void k_fc2(const float* __restrict__ h, const float* __restrict__ w,
                      const float* __restrict__ b, float* __restrict__ ct,
                      float* __restrict__ cs) {
  int i = blockIdx.x * 256 + threadIdx.x;      // 524288
  int k = i >> 9, d = i & 511;
  const float4* hr = (const float4*)(h + (long)k * HH);
  const float4* wr = (const float4*)(w + (long)d * HH);
  float s = b[d];
  for (int j = 0; j < HH / 4; j++) {
    float4 a = hr[j], bb = wr[j];
    s += a.x * bb.x + a.y * bb.y + a.z * bb.z + a.w * bb.w;
  }
  ct[i] = s;
  cs[i] = sigm_acc(s);
}

// ---- generic tiled SGEMM: C[M,Nc] = Af(A) @ Bf(B) ---------------------------
template <int AM, int BM>
__launch_bounds__(256)
__global__ void gemm64(const float* __restrict__ A, const float* __restrict__ B,
                       const float* __restrict__ dscale, float* __restrict__ C,
                       int M, int Nc, int Kr) {
  __shared__ __align__(16) float as[32][68];   // [kr][m]
  __shared__ __align__(16) float bs[32][68];   // [kr][n]
  int tid = threadIdx.x;
  int tx = tid & 15, ty = tid >> 4;
  int m0 = blockIdx.y * 64, n0 = blockIdx.x * 64;
  float acc[4][4] = {};
  for (int kt = 0; kt < Kr; kt += 32) {
    for (int s = tid; s < 512; s += 256) {
      int m = s >> 3, c4 = (s & 7) << 2;
      int gr = m0 + m, gc = kt + c4;
      float4 v = *(const float4*)&A[(long)gr * Kr + gc];
      float vv[4] = {v.x, v.y, v.z, v.w};
      if (AM == 1) {
#pragma unroll
        for (int q = 0; q < 4; q++) if (gc + q == gr) vv[q] = 1.0f;
      } else if (AM == 2) {
#pragma unroll
        for (int q = 0; q < 4; q++) if (gc + q == gr) vv[q] = 0.0f;
      }
      as[c4 + 0][m] = vv[0]; as[c4 + 1][m] = vv[1];
      as[c4 + 2][m] = vv[2]; as[c4 + 3][m] = vv[3];
    }
    for (int s = tid; s < 512; s += 256) {
      int r = s >> 4, c4 = (s & 15) << 2;
      float4 v = *(const float4*)&B[(long)(kt + r) * Nc + n0 + c4];
      if (BM == 1) {
        float sc = dscale[kt + r];
        v.x *= sc; v.y *= sc; v.z *= sc; v.w *= sc;
      }
      *(float4*)&bs[r][c4] = v;
    }
    __syncthreads();
#pragma unroll
    for (int r = 0; r < 32; r++) {
      float4 a4 = *(const float4*)&as[r][ty * 4];
      float4 b4 = *(const float4*)&bs[r][tx * 4];
      float av[4] = {a4.x, a4.y, a4.z, a4.w};
      float bv[4] = {b4.x, b4.y, b4.z, b4.w};
#pragma unroll
      for (int i = 0; i < 4; i++)
#pragma unroll
        for (int j = 0; j < 4; j++) acc[i][j] += av[i] * bv[j];
    }
    __syncthreads();
  }
#pragma unroll
  for (int i = 0; i < 4; i++) {
    float4 v = make_float4(acc[i][0], acc[i][1], acc[i][2], acc[i][3]);
    *(float4*)&C[(long)(m0 + ty * 4 + i) * Nc + n0 + tx * 4] = v;
  }
}

// ---- fused dual SGEMM: Cz = zerodiag(A) @ B ; Ci = identdiag(A) @ (dscale⊙B)
__launch_bounds__(256)
__global__ void gemm64_dual(const float* __restrict__ A, const float* __restrict__ B,
                            const float* __restrict__ dscale,
                            float* __restrict__ Cz, float* __restrict__ Ci,
                            int M, int Nc, int Kr) {
  __shared__ __align__(16) float asZ[32][68];  // zero-diag A   [kr][m]
  __shared__ __align__(16) float asI[32][68];  // ident-diag A  [kr][m]
  __shared__ __align__(16) float bs[32][68];   // raw B         [kr][n]
  __shared__ float dsc[32];
  int tid = threadIdx.x;
  int tx = tid & 15, ty = tid >> 4;
  int m0 = blockIdx.y * 64, n0 = blockIdx.x * 64;
  float accZ[4][4] = {};
  float accI[4][4] = {};
  for (int kt = 0; kt < Kr; kt += 32) {
    for (int s = tid; s < 512; s += 256) {
      int m = s >> 3, c4 = (s & 7) << 2;
      int gr = m0 + m, gc = kt + c4;
      float4 v = *(const float4*)&A[(long)gr * Kr + gc];
      float vz[4] = {v.x, v.y, v.z, v.w};
      float vi[4] = {v.x, v.y, v.z, v.w};
#pragma unroll
      for (int q = 0; q < 4; q++) if (gc + q == gr) { vz[q] = 0.0f; vi[q] = 1.0f; }
      asZ[c4 + 0][m] = vz[0]; asZ[c4 + 1][m] = vz[1];
      asZ[c4 + 2][m] = vz[2]; asZ[c4 + 3][m] = vz[3];
      asI[c4 + 0][m] = vi[0]; asI[c4 + 1][m] = vi[1];
      asI[c4 + 2][m] = vi[2]; asI[c4 + 3][m] = vi[3];
    }
    for (int s = tid; s < 512; s += 256) {
      int r = s >> 4, c4 = (s & 15) << 2;
      float4 v = *(const float4*)&B[(long)(kt + r) * Nc + n0 + c4];
      *(float4*)&bs[r][c4] = v;
    }
    if (tid < 32) dsc[tid] = dscale[kt + tid];
    __syncthreads();
#pragma unroll
    for (int r = 0; r < 32; r++) {
      float4 aZ = *(const float4*)&asZ[r][ty * 4];
      float4 aI = *(const float4*)&asI[r][ty * 4];
      float4 b4 = *(const float4*)&bs[r][tx * 4];
      float sc = dsc[r];
      float az[4] = {aZ.x, aZ.y, aZ.z, aZ.w};
      float ai[4] = {aI.x, aI.y, aI.z, aI.w};
      float bz[4] = {b4.x, b4.y, b4.z, b4.w};
      float bi[4] = {b4.x * sc, b4.y * sc, b4.z * sc, b4.w * sc};
#pragma unroll
      for (int i = 0; i < 4; i++)
#pragma unroll
        for (int j = 0; j < 4; j++) {
          accZ[i][j] += az[i] * bz[j];
          accI[i][j] += ai[i] * bi[j];
        }
    }
    __syncthreads();
  }
#pragma unroll
  for (int i = 0; i < 4; i++) {
    float4 vz = make_float4(accZ[i][0], accZ[i][1], accZ[i][2], accZ[i][3]);
    float4 vi = make_float4(accI[i][0], accI[i][1], accI[i][2], accI[i][3]);
    *(float4*)&Cz[(long)(m0 + ty * 4 + i) * Nc + n0 + tx * 4] = vz;
    *(float4*)&Ci[(long)(m0 + ty * 4 + i) * Nc + n0 + tx * 4] = vi;
  }
}

// ---- row sum-of-squares of ccb -> cn2[1024]; also zero rescue counter -------
__global__ void k_cnorm(const float* __restrict__ ccb, float* __restrict__ cn2,
                        int* __restrict__ rc) {
  if (blockIdx.x == 0 && threadIdx.x == 0) *rc = 0;
  int row = blockIdx.x * 4 + (threadIdx.x >> 6);
  int lane = threadIdx.x & 63;
  const float* r = ccb + (long)row * DD;
  float s = 0.0f;
  for (int q = 0; q < DD; q += 64) { float v = r[lane + q]; s += v * v; }
  for (int off = 32; off > 0; off >>= 1) s += __shfl_down(s, off);
  if (lane == 0) cn2[row] = s;
}

// ---- split fp32 -> bf16 hi + bf16 lo (RNE, manual bit twiddling) ------------
__device__ __forceinline__ ushort bf16_rne(float f, float* back) {
  unsigned int b = __float_as_uint(f);
  unsigned int r = b + 0x7fffu + ((b >> 16) & 1u);
  ushort h = (ushort)(r >> 16);
  *back = __uint_as_float(((unsigned int)h) << 16);
  return h;
}

// codes split: cached normally (codes must stay L2-resident for argmin)
__global__ void k_split(const float4* __restrict__ src, ushort* __restrict__ hi,
                        ushort* __restrict__ lo, long n4) {
  long i = (long)blockIdx.x * 256 + threadIdx.x;
  if (i >= n4) return;
  float4 v = src[i];
  float vv[4] = {v.x, v.y, v.z, v.w};
  ushort h[4], l[4];
#pragma unroll
  for (int q = 0; q < 4; q++) {
    float back;
    h[q] = bf16_rne(vv[q], &back);
    float rem = vv[q] - back;
    float dummy;
    l[q] = bf16_rne(rem, &dummy);
  }
  ((ushort4*)hi)[i] = make_ushort4(h[0], h[1], h[2], h[3]);
  ((ushort4*)lo)[i] = make_ushort4(l[0], l[1], l[2], l[3]);
}

// x split: pure stream, no reuse -> non-temporal both sides (keep L2 for codes)
__global__ void k_split_nt(const float* __restrict__ src, ushort* __restrict__ hi,
                           ushort* __restrict__ lo, long n4) {
  long i = (long)blockIdx.x * 256 + threadIdx.x;
  if (i >= n4) return;
  f32x4 v = __builtin_nontemporal_load((const f32x4*)src + i);
  ushort h[4], l[4];
#pragma unroll
  for (int q = 0; q < 4; q++) {
    float back;
    h[q] = bf16_rne(v[q], &back);
    float rem = v[q] - back;
    float dummy;
    l[q] = bf16_rne(rem, &dummy);
  }
  u16x4 hv = {h[0], h[1], h[2], h[3]};
  u16x4 lv = {l[0], l[1], l[2], l[3]};
  __builtin_nontemporal_store(hv, (u16x4*)hi + i);
  __builtin_nontemporal_store(lv, (u16x4*)lo + i);
}

// ---- MFMA split-bf16 argmin: d2[n,k] = cn2[k] - 2 * x_n . ccb_k -------------
// Round-6 verified kernel (400 us): persistent-x streaming + sched_barrier-
// pinned pipeline, 1024 blocks x 512 thr (8 waves, 1 block/CU).
__launch_bounds__(512, 2)
__global__ void k_argmin_mfma(const ushort* __restrict__ xh, const ushort* __restrict__ xl,
                              const ushort* __restrict__ ch, const ushort* __restrict__ cl,
                              const float* __restrict__ cn2, int* __restrict__ idxg,
                              int* __restrict__ rc, int* __restrict__ rlist) {
  __shared__ __align__(16) ushort xsh[64 * 512];   // 64 KB, row = 1KB
  __shared__ __align__(16) ushort xsl[64 * 512];   // 64 KB
  __shared__ float cn2s[KK];                       // 4 KB
  __shared__ float mm1[8][64], mm2[8][64];         // 4 KB
  __shared__ int   mid[8][64];                     // 2 KB

  int tid = threadIdx.x;
  long n0 = (long)blockIdx.x * 64;

  // ---- prologue: stage x tile (hi+lo) into LDS, swizzled, non-temporal ----
  u32x4 tmp[16];
#pragma unroll
  for (int r = 0; r < 16; r++) {
    int g = tid + r * 512;                  // 0..8191
    int rid = g >> 6;                       // 0..127
    int node = rid & 63;
    int gb = (g & 63) << 4;                 // byte within row
    const ushort* src = ((rid < 64) ? xh : xl) + (n0 + node) * (long)DD;
    tmp[r] = __builtin_nontemporal_load((const u32x4*)((const char*)src + gb));
  }
  for (int s = tid; s < KK; s += 512) cn2s[s] = cn2[s];
#pragma unroll
  for (int r = 0; r < 16; r++) {
    int g = tid + r * 512;
    int rid = g >> 6;
    int node = rid & 63;
    int gb = (g & 63) << 4;
    int db = gb ^ ((node & 7) << 4);        // XOR swizzle (write side)
    ushort* dst = (rid < 64) ? xsh : xsl;
    *(u32x4*)((char*)dst + node * 1024 + db) = tmp[r];
  }
  __syncthreads();

  int lane = tid & 63, wave = tid >> 6;     // 8 waves
  int col = lane & 15, quad = lane >> 4;

  // per-lane LDS byte bases for A fragments: addr(i,k) = abase[i] ^ (k<<6)
  int abase[4];
#pragma unroll
  for (int i = 0; i < 4; i++) {
    int node = i * 16 + col;
    abase[i] = node * 1024 + ((quad ^ (node & 3)) << 4) + (((node >> 2) & 1) << 6);
  }

  // per-lane B pointers, j-indexed (compile-time idx only): row = cb0 + j*16 + col
  const ushort* pBh[4];
  const ushort* pBl[4];
#pragma unroll
  for (int j = 0; j < 4; j++) {
    long row = (long)(wave * 64 + j * 16 + col);
    pBh[j] = ch + row * DD + quad * 8;
    pBl[j] = cl + row * DD + quad * 8;
  }

  float m1[16], m2[16]; int id1[16];
#pragma unroll
  for (int s = 0; s < 16; s++) { m1[s] = 3.4e38f; m2[s] = 3.4e38f; id1[s] = 0; }

  const float4v vzero = {0.0f, 0.0f, 0.0f, 0.0f};
  float4v acc[4][4];
  short8 aH[4], aL[4];
  short8 bh0[4], bl0[4], bh1[4], bl1[4];

#define LDA(K)                                                                   \
  do {                                                                           \
    int k_ = (K);                                                                \
    _Pragma("unroll") for (int i = 0; i < 4; i++) {                              \
      int ao_ = abase[i] ^ (k_ << 6);                                            \
      aH[i] = *(const short8*)((const char*)xsh + ao_);                          \
      aL[i] = *(const short8*)((const char*)xsl + ao_);                          \
    }                                                                            \
  } while (0)

#define LDB(K, BH, BL)                                                           \
  do {                                                                           \
    int k_ = (K);                                                                \
    _Pragma("unroll") for (int j = 0; j < 4; j++) {                              \
      BH[j] = *(const short8*)(pBh[j] + k_ * 32);                                \
      BL[j] = *(const short8*)(pBl[j] + k_ * 32);                                \
    }                                                                            \
  } while (0)

#define COMP(BH, BL)                                                             \
  do {                                                                           \
    __builtin_amdgcn_s_setprio(1);                                               \
    _Pragma("unroll") for (int j = 0; j < 4; j++)                                \
      _Pragma("unroll") for (int i = 0; i < 4; i++) {                            \
        acc[i][j] = __builtin_amdgcn_mfma_f32_16x16x32_bf16(aH[i], BH[j], acc[i][j], 0, 0, 0); \
        acc[i][j] = __builtin_amdgcn_mfma_f32_16x16x32_bf16(aH[i], BL[j], acc[i][j], 0, 0, 0); \
        acc[i][j] = __builtin_amdgcn_mfma_f32_16x16x32_bf16(aL[i], BH[j], acc[i][j], 0, 0, 0); \
      }                                                                          \
    __builtin_amdgcn_s_setprio(0);                                               \
  } while (0)

  for (int cc = 0; cc < 2; cc++) {
#pragma unroll
    for (int i = 0; i < 4; i++)
#pragma unroll
      for (int j = 0; j < 4; j++) acc[i][j] = vzero;

    LDB(0, bh0, bl0);
#pragma unroll 1
    for (int k = 0; k < 16; k += 2) {
      LDA(k);
      LDB(k + 1, bh1, bl1);
      __builtin_amdgcn_sched_barrier(0);
      COMP(bh0, bl0);                       // consumes A[k], B[k]
      __builtin_amdgcn_sched_barrier(0);
      LDA(k + 1);
      LDB((k + 2) & 15, bh0, bl0);          // k=14: dead in-bounds prefetch
      __builtin_amdgcn_sched_barrier(0);
      COMP(bh1, bl1);                       // consumes A[k+1], B[k+1]
      __builtin_amdgcn_sched_barrier(0);
    }

    // epilogue: fold this chunk into per-slot top-2
    int cb0 = cc * 512 + wave * 64;
#pragma unroll
    for (int j = 0; j < 4; j++) {
      int code = cb0 + j * 16 + col;
      float c2 = cn2s[code];
#pragma unroll
      for (int i = 0; i < 4; i++) {
#pragma unroll
        for (int r = 0; r < 4; r++) {
          float v = fmaf(-2.0f, acc[i][j][r], c2);
          int s = i * 4 + r;
          if (v < m1[s] || (v == m1[s] && code < id1[s])) {
            m2[s] = m1[s]; m1[s] = v; id1[s] = code;
          } else if (v < m2[s]) {
            m2[s] = v;
          }
        }
      }
    }
    // advance B pointers to second 512-code chunk
#pragma unroll
    for (int j = 0; j < 4; j++) { pBh[j] += 512 * DD; pBl[j] += 512 * DD; }
  }
#undef LDA
#undef LDB
#undef COMP

  // cross-lane top-2 merge over the 16 lanes of each quad-group
#pragma unroll
  for (int s = 0; s < 16; s++) {
#pragma unroll
    for (int mask = 1; mask <= 8; mask <<= 1) {
      float om1 = __shfl_xor(m1[s], mask);
      float om2 = __shfl_xor(m2[s], mask);
      int   oid = __shfl_xor(id1[s], mask);
      if (om1 < m1[s] || (om1 == m1[s] && oid < id1[s])) {
        m2[s] = fminf(m1[s], om2); m1[s] = om1; id1[s] = oid;
      } else {
        m2[s] = fminf(m2[s], om1);
      }
    }
  }
  if (col == 0) {   // lanes 0,16,32,48: one writer per quad
#pragma unroll
    for (int s = 0; s < 16; s++) {
      int i = s >> 2, r = s & 3;
      int nl = i * 16 + quad * 4 + r;
      mm1[wave][nl] = m1[s]; mm2[wave][nl] = m2[s]; mid[wave][nl] = id1[s];
    }
  }
  __syncthreads();
  if (tid < 64) {
    float f1 = mm1[0][tid], f2 = mm2[0][tid]; int fi = mid[0][tid];
#pragma unroll
    for (int w = 1; w < 8; w++) {
      float b1 = mm1[w][tid], b2 = mm2[w][tid]; int bi = mid[w][tid];
      if (b1 < f1 || (b1 == f1 && bi < fi)) {
        f2 = fminf(f1, b2); f1 = b1; fi = bi;
      } else {
        f2 = fminf(f2, b1);
      }
    }
    idxg[n0 + tid] = fi;
    if (f2 - f1 < RES_TAU) {
      int p = atomicAdd(rc, 1);
      if (p < RES_CAP) rlist[p] = (int)(n0 + tid);
    }
  }
}

// ---- exact fp32 rescue for near-tie nodes -----------------------------------
__global__ void k_rescue(const float* __restrict__ x, const float* __restrict__ ccb,
                         const float* __restrict__ cn2, const int* __restrict__ rc,
                         const int* __restrict__ rlist, int* __restrict__ idxg) {
  __shared__ float xs[DD];
  __shared__ float bv[256]; __shared__ int bi[256];
  int count = *rc; if (count > RES_CAP) count = RES_CAP;
  int tid = threadIdx.x;
  for (int f = blockIdx.x; f < count; f += gridDim.x) {
    int n = rlist[f];
    for (int s = tid; s < DD; s += 256) xs[s] = x[(long)n * DD + s];
    __syncthreads();
    float best = 3.4e38f; int besti = 0;
    for (int c = tid; c < KK; c += 256) {
      const float4* cr = (const float4*)(ccb + (long)c * DD);
      const float4* xr = (const float4*)xs;
      float dot = 0.0f;
      for (int d = 0; d < DD / 4; d++) {
        float4 a = xr[d], b = cr[d];
        dot += a.x * b.x + a.y * b.y + a.z * b.z + a.w * b.w;
      }
      float v = cn2[c] - 2.0f * dot;
      if (v < best || (v == best && c < besti)) { best = v; besti = c; }
    }
    bv[tid] = best; bi[tid] = besti;
    __syncthreads();
    for (int off = 128; off > 0; off >>= 1) {
      if (tid < off) {
        float ov = bv[tid + off]; int oi = bi[tid + off];
        if (ov < bv[tid] || (ov == bv[tid] && oi < bi[tid])) { bv[tid] = ov; bi[tid] = oi; }
      }
      __syncthreads();
    }
    if (tid == 0) idxg[n] = bi[0];
    __syncthreads();
  }
}

// ---- z gather: z[n,:] = ct[idx[n],:] ----------------------------------------
__global__ void k_gather(const float4* __restrict__ ct4, const int* __restrict__ idxg,
                         float4* __restrict__ z4) {
  long i = (long)blockIdx.x * 256 + threadIdx.x;  // over NN*128 float4
  int n = (int)(i >> 7), c = (int)(i & 127);
  z4[i] = ct4[(long)idxg[n] * 128 + c];
}

// ---- pooled means -----------------------------------------------------------
__global__ void k_pool(const float* __restrict__ x, const float* __restrict__ ccb,
                       const float* __restrict__ kcb, const int* __restrict__ idxg,
                       float* __restrict__ px, float* __restrict__ pc,
                       float* __restrict__ pk) {
  __shared__ int sidx[NPG];
  int g = blockIdx.x, tid = threadIdx.x;   // 512 threads
  if (tid < NPG) sidx[tid] = idxg[g * NPG + tid];
  __syncthreads();
  int d = tid;
  float sx = 0.0f, sc = 0.0f, sk = 0.0f;
  for (int n = 0; n < NPG; n++) {
    sx += x[((long)g * NPG + n) * DD + d];
    long r = (long)sidx[n] * DD + d;
    sc += ccb[r]; sk += kcb[r];
  }
  px[(long)g * DD + d] = sx / 128.0f;
  pc[(long)g * DD + d] = (sx + sc) / 128.0f;
  pk[(long)g * DD + d] = sk / 128.0f;
}

// ---- classifier heads -------------------------------------------------------
__global__ void k_heads(const float* __restrict__ pc, const float* __restrict__ pk,
                        const float* __restrict__ px, const float* __restrict__ w,
                        const float* __restrict__ b, float* __restrict__ cpre,
                        float* __restrict__ kpre, float* __restrict__ ypre) {
  int g = blockIdx.x, t = threadIdx.x;   // 64 threads, 30 active
  if (t >= 30) return;
  int which = t / 10, tt = t % 10;
  const float* src = (which == 0) ? pc : ((which == 1) ? pk : px);
  const float* sr = src + (long)g * DD;
  const float* wr = w + (long)tt * DD;
  float s = 0.0f;
  for (int d = 0; d < DD; d++) s += sr[d] * wr[d];
  s += b[tt];
  float* dst = (which == 0) ? cpre : ((which == 1) ? kpre : ypre);
  dst[g * TT + tt] = s;
}

// ---- x passthrough (pure stream -> non-temporal) ----------------------------
__global__ void k_copy(const float* __restrict__ src, float* __restrict__ dst) {
  long i = (long)blockIdx.x * 256 + threadIdx.x;
  f32x4 v = __builtin_nontemporal_load((const f32x4*)src + i);
  __builtin_nontemporal_store(v, (f32x4*)dst + i);
}

// ---- per-graph adjacency via MFMA split-bf16: sigmoid(norm(Z)norm(Z)^T/0.1) --
// 1 block = 1 graph, 512 thr (8 waves). Row norms (fp32) -> normalized rows
// split to bf16 hi/lo staged in LDS (two 256-dim K-halves, 128 KB) -> Gram via
// the same 3-MFMA hh/hl/lh chain + swizzle algebra as the verified argmin.
// Dropped ll term ~4e-6 absolute pre-sigmoid. Gram is symmetric so the
// C-layout orientation cannot produce a transpose error.
__launch_bounds__(512)
__global__ void k_adj(const float* __restrict__ Z, float* __restrict__ Aout) {
  __shared__ float nrm[NPG];
  __shared__ float inv[NPG];
  __shared__ __align__(16) ushort zh[NPG * 256];   // 64 KB, row = 512 B
  __shared__ __align__(16) ushort zl[NPG * 256];   // 64 KB

  int tid = threadIdx.x;
  int g = blockIdx.x;
  const float* base = Z + (long)g * NPG * DD;
  if (tid < NPG) nrm[tid] = 0.0f;
  __syncthreads();
  // row sum-of-squares: 16384 float4 over 512 threads
  for (int k = 0; k < 32; k++) {
    long i = (long)k * 512 + tid;
    int n = (int)(i >> 7);
    float4 v = ((const float4*)base)[i];
    float s = v.x * v.x + v.y * v.y + v.z * v.z + v.w * v.w;
    for (int off = 32; off > 0; off >>= 1) s += __shfl_down(s, off);
    if ((tid & 63) == 0) atomicAdd(&nrm[n], s);
  }
  __syncthreads();
  if (tid < NPG) inv[tid] = 1.0f / fmaxf(sqrtf(nrm[tid]), 1e-12f);

  int lane = tid & 63, wave = tid >> 6;   // 8 waves
  int col = lane & 15, quad = lane >> 4;
  int wy = wave >> 1, wx = wave & 1;      // 4x2 wave grid: 32-row x 64-col blocks

  const float4v vzero = {0.0f, 0.0f, 0.0f, 0.0f};
  float4v acc[2][4];
#pragma unroll
  for (int i = 0; i < 2; i++)
#pragma unroll
    for (int j = 0; j < 4; j++) acc[i][j] = vzero;

  for (int half = 0; half < 2; half++) {
    __syncthreads();   // inv visible (half 0) / prior half's reads done (half 1)
    // stage normalized bf16 hi/lo: 4096 granules of 16 B, 8 per thread
    for (int it = 0; it < 8; it++) {
      int gi = tid + it * 512;            // 0..4095
      int row = gi >> 5;                  // 0..127
      int gr  = gi & 31;                  // 16-B granule within 512-B row
      const float4* src = (const float4*)(base + (long)row * DD + half * 256 + gr * 8);
      float4 v0 = src[0], v1 = src[1];
      float iv = inv[row];
      float vv[8] = {v0.x * iv, v0.y * iv, v0.z * iv, v0.w * iv,
                     v1.x * iv, v1.y * iv, v1.z * iv, v1.w * iv};
      short8 hv, lv;
#pragma unroll
      for (int q = 0; q < 8; q++) {
        float back, dummy;
        hv[q] = (short)bf16_rne(vv[q], &back);
        lv[q] = (short)bf16_rne(vv[q] - back, &dummy);
      }
      int db = (gr << 4) ^ ((row & 7) << 4);      // XOR swizzle (write side)
      *(short8*)((char*)zh + row * 512 + db) = hv;
      *(short8*)((char*)zl + row * 512 + db) = lv;
    }
    __syncthreads();
    // Gram over this K-half: 8 k-steps of 32 dims
#pragma unroll
    for (int k = 0; k < 8; k++) {
      short8 bh[4], bl[4];
#pragma unroll
      for (int j = 0; j < 4; j++) {
        int ro = wx * 64 + j * 16 + col;
        int ao = ro * 512 + ((((k << 6) | (quad << 4))) ^ ((ro & 7) << 4));
        bh[j] = *(const short8*)((const char*)zh + ao);
        bl[j] = *(const short8*)((const char*)zl + ao);
      }
      short8 ah[2], al[2];
#pragma unroll
      for (int i = 0; i < 2; i++) {
        int ro = wy * 32 + i * 16 + col;
        int ao = ro * 512 + ((((k << 6) | (quad << 4))) ^ ((ro & 7) << 4));
        ah[i] = *(const short8*)((const char*)zh + ao);
        al[i] = *(const short8*)((const char*)zl + ao);
      }
      __builtin_amdgcn_s_setprio(1);
#pragma unroll
      for (int j = 0; j < 4; j++)
#pragma unroll
        for (int i = 0; i < 2; i++) {
          acc[i][j] = __builtin_amdgcn_mfma_f32_16x16x32_bf16(ah[i], bh[j], acc[i][j], 0, 0, 0);
          acc[i][j] = __builtin_amdgcn_mfma_f32_16x16x32_bf16(ah[i], bl[j], acc[i][j], 0, 0, 0);
          acc[i][j] = __builtin_amdgcn_mfma_f32_16x16x32_bf16(al[i], bh[j], acc[i][j], 0, 0, 0);
        }
      __builtin_amdgcn_s_setprio(0);
    }
  }

  // epilogue: C row = A-row (quad*4+r), C col = B-row (col)  [argmin-verified]
  float* aout = Aout + (long)g * NPG * NPG;
#pragma unroll
  for (int i = 0; i < 2; i++) {
#pragma unroll
    for (int r = 0; r < 4; r++) {
      int a = wy * 32 + i * 16 + quad * 4 + r;
#pragma unroll
      for (int j = 0; j < 4; j++) {
        int b = wx * 64 + j * 16 + col;
        aout[(long)a * NPG + b] = sigm_fast(acc[i][j][r] * 10.0f);
      }
    }
  }
}

extern "C" void kernel_launch(void* const* d_in, const int* in_sizes, int n_in,
                              void* d_out, int out_size, void* d_ws, size_t ws_size,
                              hipStream_t stream) {
  const float* x      = (const float*)d_in[0];
  const float* cbi    = (const float*)d_in[2];
  const float* fc1w   = (const float*)d_in[3];
  const float* fc1b   = (const float*)d_in[4];
  const float* fc2w   = (const float*)d_in[5];
  const float* fc2b   = (const float*)d_in[6];
  const float* causal = (const float*)d_in[7];
  const float* clsw   = (const float*)d_in[8];
  const float* clsb   = (const float*)d_in[9];
  float* out = (float*)d_out;

  float* cpre = out + OFF_CPRE;
  float* kpre = out + OFF_KPRE;
  float* ypre = out + OFF_YPRE;

  // scratch carved out of the A_ori region (overwritten by final k_adj)
  float* scr  = out + OFF_AORI;
  float* h    = scr;
  float* cs   = scr + 131072L;
  float* tmp2 = scr + 655360L;
  float* ccb  = scr + 1179648L;
  float* kcb  = scr + 1703936L;
  float* cn2  = scr + 2228224L;
  int*   idxg = (int*)(scr + 2229248L);
  float* pk   = scr + 2294784L;
  float* dv   = scr + 2556928L;
  ushort* ch  = (ushort*)(scr + 2557952L);  // 1024x512 bf16 hi (262144 floats)
  ushort* cl  = (ushort*)(scr + 2820096L);  // 1024x512 bf16 lo
  int*   rc   = (int*)(scr + 3082240L);     // rescue counter
  int*   rlist= (int*)(scr + 3082496L);     // rescue list (65536 ints)
  float* ct   = out + OFF_AREC;             // lives in A_rec region until gather done
  // x hi/lo split lives in the X output region until k_copy (runs after argmin+rescue)
  ushort* xh  = (ushort*)(out + OFF_X);                 // 65536x512 bf16 hi
  ushort* xl  = (ushort*)(out + OFF_X + 16777216L);     // 65536x512 bf16 lo

  k_diagmask<<<4096, 256, 0, stream>>>(causal, out + OFF_CD, out + OFF_CM, dv);
  k_fc1<<<512, 256, 0, stream>>>(cbi, fc1w, fc1b, h);
  k_fc2<<<2048, 256, 0, stream>>>(h, fc2w, fc2b, ct, cs);
  gemm64_dual<<<dim3(8, 16), 256, 0, stream>>>(causal, cs, dv, tmp2, ccb, KK, DD, KK);
  gemm64<1, 0><<<dim3(8, 16), 256, 0, stream>>>(causal, tmp2, nullptr, kcb, KK, DD, KK);
  k_cnorm<<<256, 256, 0, stream>>>(ccb, cn2, rc);
  k_split_nt<<<32768, 256, 0, stream>>>(x, xh, xl, 8388608L);
  k_split<<<512, 256, 0, stream>>>((const float4*)ccb, ch, cl, 131072L);
  k_argmin_mfma<<<1024, 512, 0, stream>>>(xh, xl, ch, cl, cn2, idxg, rc, rlist);
  k_rescue<<<128, 256, 0, stream>>>(x, ccb, cn2, rc, rlist, idxg);
  k_gather<<<32768, 256, 0, stream>>>((const float4*)ct, idxg, (float4*)(out + OFF_Z));
  k_pool<<<512, 512, 0, stream>>>(x, ccb, kcb, idxg, out + OFF_PX, out + OFF_PC, pk);
  k_heads<<<512, 64, 0, stream>>>(out + OFF_PC, pk, out + OFF_PX, clsw, clsb, cpre, kpre, ypre);
  k_copy<<<32768, 256, 0, stream>>>(x, out + OFF_X);
  k_adj<<<512, 512, 0, stream>>>(out + OFF_Z, out + OFF_AREC);  // overwrites ct (done)
  k_adj<<<512, 512, 0, stream>>>(x, out + OFF_AORI);            // overwrites scratch (done)
}